// Round 8
// baseline (240.605 us; speedup 1.0000x reference)
//
#include <hip/hip_runtime.h>
#include <hip/hip_bf16.h>

// Problem: x (16,256,32,32) fp32, weight (8193,256) fp32 (emb = first 8192 rows).
// Rows: r = b*1024 + (h*32+w), xf[r][c] = x[b*262144 + c*1024 + (r&1023)].
// Outputs (flat fp32): xq (4194304) | loss (1) | code-as-float (16384).
//
// R8: A-fragments (codes, eh) read DIRECTLY from global (row-major eh, L2-
// resident 4.2MB) instead of via LDS: halves K-loop ds_reads (LDS pipe was
// the co-limiter at ~192cyc vs 155cyc MFMA per chunk) and halves the
// global_load_lds staging drained at each barrier. B (xrows) stays gll16-
// staged + swizzled. prep-e simplified (no swizzle). Epilogue scratch in Bs.

#define N_ROWS   16384
#define KCODES   8192
#define DIM      256
#define LOSS_OFF 4194304
#define CODE_OFF 4194305
#define MARGIN_ACC 0.006f          // covers f16 noise (~8e-4 rms) + 4.9e-4 idx-mask quant

typedef _Float16 half8  __attribute__((ext_vector_type(8)));
typedef _Float16 half4v __attribute__((ext_vector_type(4)));
typedef float    float4v __attribute__((ext_vector_type(4)));
typedef unsigned long long u64;

__device__ __forceinline__ unsigned umax32(unsigned a, unsigned b) { return a > b ? a : b; }
__device__ __forceinline__ unsigned umin32(unsigned a, unsigned b) { return a < b ? a : b; }
__device__ __forceinline__ void gll16(const _Float16* g, _Float16* l) {
  __builtin_amdgcn_global_load_lds((const __attribute__((address_space(1))) void*)g,
                                   (__attribute__((address_space(3))) void*)l, 16, 0, 0);
}

// xh swizzled tile layout (for gll16 B-staging): per 128-row tile, per 64-half
// K-chunk, 16B unit u = row_local*8 + (kgrp ^ (row_local & 7)).
// eh: plain row-major [8192][256] halves (A-frags read direct from global).

// ---------------------------------------------------------------- fused prep (+ Sxx)
__global__ __launch_bounds__(256) void k_prep(const float* __restrict__ x, _Float16* __restrict__ xh,
                                              const float* __restrict__ wt, _Float16* __restrict__ eh,
                                              float* __restrict__ en2c, double* __restrict__ dacc) {
  __shared__ float lsx[128 * 65];               // x path: [n][c'] fp32, stride 65
  __shared__ float es[32];
  int t = threadIdx.x;
  int lane = t & 63, wv = t >> 6;
  if (blockIdx.x < 128) {
    // ---- x path: 128 blocks x 128 rows (block == xh row-tile)
    int blk  = blockIdx.x;
    int row0 = blk * 128;
    int b    = row0 >> 10;
    int n0   = row0 & 1023;
    const float* xb = x + (size_t)b * 262144 + n0;   // xb[c*1024 + n_local]
    int n_l = t & 127, cg = t >> 7;                  // 2 c-groups x 128 n
    float sxx = 0.f;
    for (int cc = 0; cc < 4; ++cc) {                 // 64-c chunk == xh K-chunk
      if (cc) __syncthreads();
      for (int j = 0; j < 32; ++j) {
        int c = cc * 64 + cg * 32 + j;
        float v = xb[(size_t)c * 1024 + n_l];        // wave: 256B contiguous
        sxx = fmaf(v, v, sxx);
        lsx[n_l * 65 + (c & 63)] = v;
      }
      __syncthreads();
#pragma unroll
      for (int i = 0; i < 4; ++i) {                  // 1024 units = 128 rows x 8
        int unit = i * 256 + t;
        int rl = unit >> 3, p = unit & 7;
        const float* src = &lsx[rl * 65 + p * 8];
        half8 h;
#pragma unroll
        for (int k2 = 0; k2 < 8; ++k2) h[k2] = (_Float16)src[k2];
        int p7 = p ^ (rl & 7);
        *(half8*)&xh[(size_t)blk * 32768 + (size_t)cc * 8192 + (size_t)rl * 64 + p7 * 8] = h;
      }
    }
#pragma unroll
    for (int d = 32; d; d >>= 1) sxx += __shfl_xor(sxx, d);
    __syncthreads();
    if (lane == 0) lsx[wv] = sxx;
    __syncthreads();
    if (t == 0) atomicAdd(&dacc[0], (double)(lsx[0] + lsx[1] + lsx[2] + lsx[3]));
  } else {
    // ---- e path: 256 blocks x 32 codes, row-major eh (no swizzle)
    int blk  = blockIdx.x - 128;
    int k0 = blk * 32;
    const float* wb = wt + (size_t)k0 * 256;
    _Float16* eb = eh + (size_t)k0 * 256;
    for (int i = 0; i < 8; ++i) {
      int lin = i * 1024 + t * 4;                 // all lanes of a wave share lin>>8 = i*4+wv
      float4v v = *(const float4v*)&wb[lin];
      half4v h; float ss = 0.f;
#pragma unroll
      for (int j = 0; j < 4; ++j) { h[j] = (_Float16)v[j]; ss = fmaf(v[j], v[j], ss); }
      *(half4v*)&eb[lin] = h;
#pragma unroll
      for (int d = 32; d; d >>= 1) ss += __shfl_xor(ss, d);
      if (lane == 0) es[i * 4 + wv] = ss;
    }
    __syncthreads();
    if (t < 32) en2c[k0 + t] = 32.0f - 0.5f * es[t];
  }
}

// ---------------------------------------------------------------- main GEMM (A=codes direct-global, B=xrows via LDS)
__global__ __launch_bounds__(256, 3) void k_gemm(const _Float16* __restrict__ xh, const _Float16* __restrict__ eh,
                                                 const float* __restrict__ en2c,
                                                 u64* __restrict__ top2) {
  __shared__ __align__(16) _Float16 Bs[8192];   // 128 xrows x 64 halves (swizzled)
  int t    = threadIdx.x;
  int bx   = blockIdx.x;   // code tile 0..63 (128 codes)
  int by   = blockIdx.y;   // xrow tile 0..127 (128 rows)
  int lane = t & 63, w = t >> 6;
  int wr = w & 1, wc = w >> 1;                  // wave: codes 64*wr, xrows 64*wc
  int ln15 = lane & 15, q = lane >> 4;
  int q4 = q * 4;

  const _Float16* Bg = xh + (size_t)by * 32768;
  // per-lane A base: code row (bx*128 + wr*64 + ln15), k-offset q*8
  const _Float16* Ab = eh + ((size_t)(bx * 128 + wr * 64) + ln15) * 256 + q * 8;

  int kwave = bx * 128 + wr * 64;
  float4v cin[4];
#pragma unroll
  for (int mi = 0; mi < 4; ++mi) cin[mi] = *(const float4v*)&en2c[kwave + mi * 16 + q4];

  float4v acc[4][4];
#pragma unroll
  for (int mi = 0; mi < 4; ++mi)
#pragma unroll
    for (int ni = 0; ni < 4; ++ni) acc[mi][ni] = cin[mi];

  int so = (w * 64 + lane) * 8;                 // staging source offset (halves)
  int lo = w * 512;                             // per-wave LDS dest offset (halves)

  for (int ch = 0; ch < 4; ++ch) {
    if (ch) __syncthreads();
    const _Float16* bc = Bg + ch * 8192;
#pragma unroll
    for (int i = 0; i < 4; ++i)
      gll16(bc + i * 2048 + so, Bs + i * 2048 + lo);
    // A-fragments: direct global loads (eh row-major, L2-resident).
    // quad q + 16 lanes cover 16 consecutive 64B lines -> fully coalesced.
    half8 af[2][4];
#pragma unroll
    for (int ks = 0; ks < 2; ++ks)
#pragma unroll
      for (int mi = 0; mi < 4; ++mi)
        af[ks][mi] = *(const half8*)(Ab + (size_t)mi * 16 * 256 + ch * 64 + ks * 32);
    __syncthreads();
#pragma unroll
    for (int ks = 0; ks < 2; ++ks) {
      half8 bf[4];
#pragma unroll
      for (int ni = 0; ni < 4; ++ni) {
        int row = wc * 64 + ni * 16 + ln15;     // xrow
        bf[ni] = *(const half8*)&Bs[(row * 8 + ((ks * 4 + q) ^ (row & 7))) * 8];
      }
#pragma unroll
      for (int mi = 0; mi < 4; ++mi)
#pragma unroll
        for (int ni = 0; ni < 4; ++ni)
          acc[mi][ni] = __builtin_amdgcn_mfma_f32_16x16x32_f16(af[ks][mi], bf[ni], acc[mi][ni], 0, 0, 0);
    }
  }

  // epilogue: per x-row top-2 (max of biased acc) over this wave's 64 codes.
  // pack = (score bits & ~0x7F) | (7-bit block-local code index).
  __syncthreads();                              // frag reads done; reuse Bs
  u64* ep = (u64*)(void*)Bs;                    // [128 xrows][2 wr]
  int ibase = wr * 64 + q4;

#pragma unroll
  for (int ni = 0; ni < 4; ++ni) {
    unsigned hi[8], lo2[8];
#pragma unroll
    for (int j = 0; j < 8; ++j) {
      int mi = j >> 1, rb = (j & 1) * 2;
      unsigned p0 = (__float_as_uint(acc[mi][ni][rb])     & 0xFFFFFF80u) | (unsigned)(ibase + mi * 16 + rb);
      unsigned p1 = (__float_as_uint(acc[mi][ni][rb + 1]) & 0xFFFFFF80u) | (unsigned)(ibase + mi * 16 + rb + 1);
      hi[j] = umax32(p0, p1); lo2[j] = umin32(p0, p1);
    }
#pragma unroll
    for (int st = 4; st; st >>= 1)
#pragma unroll
      for (int j = 0; j < 8; ++j) if (j < st) {
        unsigned nb = umax32(hi[j], hi[j + st]);
        unsigned ns = umax32(umin32(hi[j], hi[j + st]), umax32(lo2[j], lo2[j + st]));
        hi[j] = nb; lo2[j] = ns;
      }
    unsigned b = hi[0], s = lo2[0];
#pragma unroll
    for (int d = 16; d < 64; d <<= 1) {
      unsigned ob = __shfl_xor(b, d);
      unsigned os = __shfl_xor(s, d);
      unsigned ns = umax32(umin32(b, ob), umax32(s, os));
      b = umax32(b, ob); s = ns;
    }
    if (q == 0) {
      int rl = wc * 64 + ni * 16 + ln15;
      ep[rl * 2 + wr] = ((u64)b << 32) | s;
    }
  }
  __syncthreads();
  if (t < 128) {
    u64 A = ep[t * 2 + 0], B = ep[t * 2 + 1];
    unsigned a0 = (unsigned)(A >> 32), a1 = (unsigned)A;
    unsigned b0 = (unsigned)(B >> 32), b1 = (unsigned)B;
    unsigned best = umax32(a0, b0);
    unsigned sec  = umax32(umin32(a0, b0), umax32(a1, b1));
    // transposed layout [bx][row]: contiguous 1KB per block.
    top2[(size_t)bx * 16384 + (size_t)by * 128 + t] = ((u64)best << 32) | sec;
  }
}

// ---------------------------------------------------------------- fused refine + gather + loss (no x in common path)
__global__ __launch_bounds__(512) void k_out(const u64* __restrict__ top2,
                                             const float* __restrict__ x, const float* __restrict__ w,
                                             float* __restrict__ out,
                                             double* __restrict__ dacc, unsigned* __restrict__ cnt) {
  __shared__ float ect[256 * 65];      // [c][r] transposed, stride 65; both phases <=2-way
  __shared__ double dpart[8];
  int t    = threadIdx.x;
  int lane = t & 63, wv = t >> 6;
  int blk  = blockIdx.x;               // 256 blocks x 64 rows
  int row0 = blk * 64;
  int b = row0 >> 10, n0 = row0 & 1023;

  // ---- phase 1: refine + inline gather + score contribution, 8 rows per wave
  double dsum = 0.0;
  for (int j = 0; j < 8; ++j) {
    int rl  = wv * 8 + j;
    int row = row0 + rl;
    u64 e = top2[(size_t)lane * 16384 + row];    // lane = code-tile; 8 rows/64B line reused over j
    unsigned hi = (unsigned)(e >> 32), lo = (unsigned)e;
    unsigned mx = hi;
#pragma unroll
    for (int d = 1; d < 64; d <<= 1) mx = umax32(mx, __shfl_xor(mx, d));
    float fm = __uint_as_float(mx & 0xFFFFFF80u);
    float th = fm - MARGIN_ACC;
    bool c0 = __uint_as_float(hi & 0xFFFFFF80u) >= th;
    bool c1 = __uint_as_float(lo & 0xFFFFFF80u) >= th;
    u64 bal0 = __ballot(c0), bal1 = __ballot(c1);
    int kbest;
    double d2c;                                  // = ||e||^2 - 2 x.e for the chosen code
    if (__popcll(bal0) + __popcll(bal1) <= 1) {
      int l0 = __ffsll((unsigned long long)__ballot(hi == mx)) - 1;
      kbest = l0 * 128 + (int)(__shfl(hi, l0) & 127u);
      d2c = 64.0 - 2.0 * (double)fm;             // quantized acc: +4.9e-4 worst-case per row
    } else {
      const float* xr = x + (size_t)b * 262144 + (row & 1023);
      float4v ex;
#pragma unroll
      for (int i = 0; i < 4; ++i) ex[i] = xr[(size_t)(lane * 4 + i) * 1024];
      double bs = 1e300; int bk = 0x7fffffff;
      for (int pass = 0; pass < 2; ++pass) {
        u64 bal = pass ? bal1 : bal0;
        unsigned src = pass ? lo : hi;
        while (bal) {
          int l = __ffsll((unsigned long long)bal) - 1;
          bal &= bal - 1;
          int kc = l * 128 + (int)(__shfl(src, l) & 127u);
          float4v wv4 = *(const float4v*)&w[(size_t)kc * DIM + lane * 4];
          double s = 0.0;
#pragma unroll
          for (int i = 0; i < 4; ++i) { double ev = (double)wv4[i]; s += ev * (ev - 2.0 * (double)ex[i]); }
#pragma unroll
          for (int d = 1; d < 64; d <<= 1) s += __shfl_xor(s, d);
          if (s < bs || (s == bs && kc < bk)) { bs = s; bk = kc; }
        }
      }
      kbest = bk;                                // all lanes agree (shuffle-reduced)
      d2c = bs;                                  // exact fp64
    }
    if (lane == 0) { out[CODE_OFF + row] = (float)kbest; dsum += d2c; }
    // inline gather: whole wave loads this row's e-vector (coalesced 256B x4)
    const float* wrow = w + (size_t)kbest * 256;
#pragma unroll
    for (int i = 0; i < 4; ++i) ect[(i * 64 + lane) * 65 + rl] = wrow[i * 64 + lane];
  }
  __syncthreads();

  // ---- phase 2: write xq (full-wave 256B txns); loss comes from scores, no x read
  const size_t base = (size_t)b * 262144 + n0 + lane;
  for (int j = 0; j < 32; ++j) {
    int c = wv * 32 + j;
    out[base + (size_t)c * 1024] = ect[c * 65 + lane];
  }
  if (lane == 0) dpart[wv] = dsum;
  __syncthreads();
  if (t == 0) {
    double s = dpart[0] + dpart[1] + dpart[2] + dpart[3] + dpart[4] + dpart[5] + dpart[6] + dpart[7];
    atomicAdd(&dacc[1], s);
    __threadfence();
    unsigned old = atomicAdd(cnt, 1u);
    if (old == 255u) {
      __threadfence();
      double sxx = *(volatile double*)&dacc[0];
      double sd2 = *(volatile double*)&dacc[1];
      out[LOSS_OFF] = (float)(1.25 * (sxx + sd2) / 4194304.0);
    }
  }
}

// ---------------------------------------------------------------- launch
extern "C" void kernel_launch(void* const* d_in, const int* in_sizes, int n_in,
                              void* d_out, int out_size, void* d_ws, size_t ws_size,
                              hipStream_t stream) {
  const float* x = (const float*)d_in[0];
  const float* w = (const float*)d_in[1];
  float* out = (float*)d_out;
  char* ws = (char*)d_ws;
  _Float16* xh   = (_Float16*)(ws);                 //  8,388,608 B (swizzled tiles)
  _Float16* eh   = (_Float16*)(ws + 8388608);       //  4,194,304 B (row-major)
  float*    en2c = (float*)(ws + 12582912);         //     32,768 B
  u64*      top2 = (u64*)(ws + 12615680);           //  8,388,608 B ([64 bx][16384 row] u64)
  double*   dacc = (double*)(ws + 21004288);        //  16 B: [0]=Sxx, [1]=sum d2
  unsigned* cnt  = (unsigned*)(ws + 21004304);      //   4 B

  hipMemsetAsync(dacc, 0, 24, stream);
  k_prep<<<384, 256, 0, stream>>>(x, xh, w, eh, en2c, dacc);
  k_gemm<<<dim3(64, 128), 256, 0, stream>>>(xh, eh, en2c, top2);
  k_out<<<256, 512, 0, stream>>>(top2, x, w, out, dacc, cnt);
}

// Round 9
// 171.339 us; speedup vs baseline: 1.4043x; 1.4043x over previous
//
#include <hip/hip_runtime.h>
#include <hip/hip_bf16.h>

// Problem: x (16,256,32,32) fp32, weight (8193,256) fp32 (emb = first 8192 rows).
// Rows: r = b*1024 + (h*32+w), xf[r][c] = x[b*262144 + c*1024 + (r&1023)].
// Outputs (flat fp32): xq (4194304) | loss (1) | code-as-float (16384).
//
// R9: k_gemm reverted to R7 (direct-global A-frags regressed: global latency
// in the MFMA chain). k_prep x-path split to 512 blocks (was 128 = half-idle
// chip on the 64MB strided x read); Sxx via per-block partial slots (memset
// launch dropped; dacc/cnt zeroed by prep block 0, consumed 2 kernels later).
// k_out at 1024 threads (16 waves/CU); last block's wave 0 sums Sxx partials.

#define N_ROWS   16384
#define KCODES   8192
#define DIM      256
#define LOSS_OFF 4194304
#define CODE_OFF 4194305
#define MARGIN_ACC 0.006f          // covers f16 noise (~8e-4 rms) + 4.9e-4 idx-mask quant

typedef _Float16 half8  __attribute__((ext_vector_type(8)));
typedef _Float16 half4v __attribute__((ext_vector_type(4)));
typedef float    float4v __attribute__((ext_vector_type(4)));
typedef unsigned long long u64;

__device__ __forceinline__ unsigned umax32(unsigned a, unsigned b) { return a > b ? a : b; }
__device__ __forceinline__ unsigned umin32(unsigned a, unsigned b) { return a < b ? a : b; }
__device__ __forceinline__ void gll16(const _Float16* g, _Float16* l) {
  __builtin_amdgcn_global_load_lds((const __attribute__((address_space(1))) void*)g,
                                   (__attribute__((address_space(3))) void*)l, 16, 0, 0);
}

// Swizzled tile layout (xh and eh): per 128-row tile, per 64-half K-chunk,
// 16B unit u = row_local*8 + (kgrp ^ (row_local & 7)); chunk = 8192 halves.

// ---------------------------------------------------------------- fused prep (+ Sxx partials)
__global__ __launch_bounds__(256) void k_prep(const float* __restrict__ x, _Float16* __restrict__ xh,
                                              const float* __restrict__ wt, _Float16* __restrict__ eh,
                                              float* __restrict__ en2c, float* __restrict__ sxxp,
                                              double* __restrict__ dacc, unsigned* __restrict__ cnt) {
  __shared__ float lsx[128 * 65];               // x path: [n][c'] fp32, stride 65
  __shared__ __align__(16) _Float16 ls[8192];   // e path: 32 codes x 256 halves
  __shared__ float es[32];
  int t = threadIdx.x;
  int lane = t & 63, wv = t >> 6;
  int bid = blockIdx.x;
  if (bid < 512) {
    // ---- x path: 512 blocks = 128 row-tiles x 4 K-chunks
    if (bid == 0 && t == 0) { dacc[0] = 0.0; *cnt = 0u; }   // consumed only in k_out
    int blk = bid >> 2, cc = bid & 3;
    int row0 = blk * 128;
    int b    = row0 >> 10;
    int n0   = row0 & 1023;
    const float* xb = x + (size_t)b * 262144 + n0;   // xb[c*1024 + n_local]
    int n_l = t & 127, cg = t >> 7;                  // 2 c-groups x 128 n
    float sxx = 0.f;
    for (int j = 0; j < 32; ++j) {
      int c = cc * 64 + cg * 32 + j;
      float v = xb[(size_t)c * 1024 + n_l];          // wave: 256B contiguous
      sxx = fmaf(v, v, sxx);
      lsx[n_l * 65 + (c & 63)] = v;                  // bank=(n+c')%32 -> 2-way
    }
    __syncthreads();
#pragma unroll
    for (int i = 0; i < 4; ++i) {                    // 1024 units = 128 rows x 8
      int unit = i * 256 + t;
      int rl = unit >> 3, p = unit & 7;
      const float* src = &lsx[rl * 65 + p * 8];
      half8 h;
#pragma unroll
      for (int k2 = 0; k2 < 8; ++k2) h[k2] = (_Float16)src[k2];
      int p7 = p ^ (rl & 7);
      *(half8*)&xh[(size_t)blk * 32768 + (size_t)cc * 8192 + (size_t)rl * 64 + p7 * 8] = h;
    }
#pragma unroll
    for (int d = 32; d; d >>= 1) sxx += __shfl_xor(sxx, d);
    __syncthreads();
    if (lane == 0) lsx[wv] = sxx;
    __syncthreads();
    if (t == 0) sxxp[bid] = lsx[0] + lsx[1] + lsx[2] + lsx[3];
  } else {
    // ---- e path: 256 blocks x 32 codes (swizzled eh)
    int blk  = bid - 512;
    int k0 = blk * 32;
    const float* wb = wt + (size_t)k0 * 256;
    for (int i = 0; i < 8; ++i) {
      int lin = i * 1024 + t * 4;                 // all lanes of a wave share lin>>8 = i*4+wv
      float4v v = *(const float4v*)&wb[lin];
      half4v h; float ss = 0.f;
#pragma unroll
      for (int j = 0; j < 4; ++j) { h[j] = (_Float16)v[j]; ss = fmaf(v[j], v[j], ss); }
      *(half4v*)&ls[lin] = h;
#pragma unroll
      for (int d = 32; d; d >>= 1) ss += __shfl_xor(ss, d);
      if (lane == 0) es[i * 4 + wv] = ss;
    }
    __syncthreads();
    size_t tb = (size_t)(k0 >> 7) * 32768;
    for (int i = 0; i < 4; ++i) {
      int u = i * 256 + t;
      int code_l = u >> 5;
      int cu = u & 31, chunk = cu >> 3, p = cu & 7;
      int kgl = k0 + code_l;
      int kg = p ^ (kgl & 7);
      half8 h = *(half8*)&ls[code_l * 256 + chunk * 64 + kg * 8];
      *(half8*)&eh[tb + (size_t)chunk * 8192 + (size_t)(kgl & 127) * 64 + p * 8] = h;
    }
    if (t < 32) en2c[k0 + t] = 32.0f - 0.5f * es[t];
  }
}

// ---------------------------------------------------------------- main GEMM (A=codes, B=xrows) + top-2 epilogue [R7]
__global__ __launch_bounds__(256) void k_gemm(const _Float16* __restrict__ xh, const _Float16* __restrict__ eh,
                                              const float* __restrict__ en2c,
                                              u64* __restrict__ top2) {
  __shared__ __align__(16) _Float16 As[8192];   // 128 codes x 64 halves (swizzled)
  __shared__ __align__(16) _Float16 Bs[8192];   // 128 xrows x 64 halves (swizzled)
  int t    = threadIdx.x;
  int bx   = blockIdx.x;   // code tile 0..63 (128 codes)
  int by   = blockIdx.y;   // xrow tile 0..127 (128 rows)
  int lane = t & 63, w = t >> 6;
  int wr = w & 1, wc = w >> 1;                  // wave: codes 64*wr, xrows 64*wc
  int ln15 = lane & 15, q = lane >> 4;
  int q4 = q * 4;

  const _Float16* Ag = eh + (size_t)bx * 32768;
  const _Float16* Bg = xh + (size_t)by * 32768;

  int kwave = bx * 128 + wr * 64;
  float4v cin[4];
#pragma unroll
  for (int mi = 0; mi < 4; ++mi) cin[mi] = *(const float4v*)&en2c[kwave + mi * 16 + q4];

  float4v acc[4][4];
#pragma unroll
  for (int mi = 0; mi < 4; ++mi)
#pragma unroll
    for (int ni = 0; ni < 4; ++ni) acc[mi][ni] = cin[mi];

  int so = (w * 64 + lane) * 8;                 // staging source offset (halves)
  int lo = w * 512;                             // per-wave LDS dest offset (halves)

  for (int ch = 0; ch < 4; ++ch) {
    if (ch) __syncthreads();
    const _Float16* ac = Ag + ch * 8192;
    const _Float16* bc = Bg + ch * 8192;
#pragma unroll
    for (int i = 0; i < 4; ++i) {
      gll16(ac + i * 2048 + so, As + i * 2048 + lo);
      gll16(bc + i * 2048 + so, Bs + i * 2048 + lo);
    }
    __syncthreads();
#pragma unroll
    for (int ks = 0; ks < 2; ++ks) {
      half8 af[4], bf[4];
#pragma unroll
      for (int mi = 0; mi < 4; ++mi) {
        int row = wr * 64 + mi * 16 + ln15;     // code row
        af[mi] = *(const half8*)&As[(row * 8 + ((ks * 4 + q) ^ (row & 7))) * 8];
      }
#pragma unroll
      for (int ni = 0; ni < 4; ++ni) {
        int row = wc * 64 + ni * 16 + ln15;     // xrow
        bf[ni] = *(const half8*)&Bs[(row * 8 + ((ks * 4 + q) ^ (row & 7))) * 8];
      }
#pragma unroll
      for (int mi = 0; mi < 4; ++mi)
#pragma unroll
        for (int ni = 0; ni < 4; ++ni)
          acc[mi][ni] = __builtin_amdgcn_mfma_f32_16x16x32_f16(af[mi], bf[ni], acc[mi][ni], 0, 0, 0);
    }
  }

  // epilogue: per x-row top-2 (max of biased acc) over this wave's 64 codes.
  __syncthreads();                              // frag reads done; reuse As
  u64* ep = (u64*)(void*)As;                    // [128 xrows][2 wr]
  int ibase = wr * 64 + q4;

#pragma unroll
  for (int ni = 0; ni < 4; ++ni) {
    unsigned hi[8], lo2[8];
#pragma unroll
    for (int j = 0; j < 8; ++j) {
      int mi = j >> 1, rb = (j & 1) * 2;
      unsigned p0 = (__float_as_uint(acc[mi][ni][rb])     & 0xFFFFFF80u) | (unsigned)(ibase + mi * 16 + rb);
      unsigned p1 = (__float_as_uint(acc[mi][ni][rb + 1]) & 0xFFFFFF80u) | (unsigned)(ibase + mi * 16 + rb + 1);
      hi[j] = umax32(p0, p1); lo2[j] = umin32(p0, p1);
    }
#pragma unroll
    for (int st = 4; st; st >>= 1)
#pragma unroll
      for (int j = 0; j < 8; ++j) if (j < st) {
        unsigned nb = umax32(hi[j], hi[j + st]);
        unsigned ns = umax32(umin32(hi[j], hi[j + st]), umax32(lo2[j], lo2[j + st]));
        hi[j] = nb; lo2[j] = ns;
      }
    unsigned b = hi[0], s = lo2[0];
#pragma unroll
    for (int d = 16; d < 64; d <<= 1) {
      unsigned ob = __shfl_xor(b, d);
      unsigned os = __shfl_xor(s, d);
      unsigned ns = umax32(umin32(b, ob), umax32(s, os));
      b = umax32(b, ob); s = ns;
    }
    if (q == 0) {
      int rl = wc * 64 + ni * 16 + ln15;
      ep[rl * 2 + wr] = ((u64)b << 32) | s;
    }
  }
  __syncthreads();
  if (t < 128) {
    u64 A = ep[t * 2 + 0], B = ep[t * 2 + 1];
    unsigned a0 = (unsigned)(A >> 32), a1 = (unsigned)A;
    unsigned b0 = (unsigned)(B >> 32), b1 = (unsigned)B;
    unsigned best = umax32(a0, b0);
    unsigned sec  = umax32(umin32(a0, b0), umax32(a1, b1));
    top2[(size_t)bx * 16384 + (size_t)by * 128 + t] = ((u64)best << 32) | sec;
  }
}

// ---------------------------------------------------------------- fused refine + gather + loss
__global__ __launch_bounds__(1024) void k_out(const u64* __restrict__ top2,
                                              const float* __restrict__ x, const float* __restrict__ w,
                                              float* __restrict__ out, const float* __restrict__ sxxp,
                                              double* __restrict__ dacc, unsigned* __restrict__ cnt) {
  __shared__ float ect[256 * 65];      // [c][r] transposed, stride 65; both phases <=2-way
  __shared__ double dpart[16];
  __shared__ unsigned oldc;
  int t    = threadIdx.x;
  int lane = t & 63, wv = t >> 6;      // 16 waves
  int blk  = blockIdx.x;               // 256 blocks x 64 rows
  int row0 = blk * 64;
  int b = row0 >> 10, n0 = row0 & 1023;

  // ---- phase 1: refine + inline gather + score contribution, 4 rows per wave
  double dsum = 0.0;
  for (int j = 0; j < 4; ++j) {
    int rl  = wv * 4 + j;
    int row = row0 + rl;
    u64 e = top2[(size_t)lane * 16384 + row];    // lane = code-tile
    unsigned hi = (unsigned)(e >> 32), lo = (unsigned)e;
    unsigned mx = hi;
#pragma unroll
    for (int d = 1; d < 64; d <<= 1) mx = umax32(mx, __shfl_xor(mx, d));
    float fm = __uint_as_float(mx & 0xFFFFFF80u);
    float th = fm - MARGIN_ACC;
    bool c0 = __uint_as_float(hi & 0xFFFFFF80u) >= th;
    bool c1 = __uint_as_float(lo & 0xFFFFFF80u) >= th;
    u64 bal0 = __ballot(c0), bal1 = __ballot(c1);
    int kbest;
    double d2c;                                  // = ||e||^2 - 2 x.e for the chosen code
    if (__popcll(bal0) + __popcll(bal1) <= 1) {
      int l0 = __ffsll((unsigned long long)__ballot(hi == mx)) - 1;
      kbest = l0 * 128 + (int)(__shfl(hi, l0) & 127u);
      d2c = 64.0 - 2.0 * (double)fm;             // quantized acc: +4.9e-4 worst-case per row
    } else {
      const float* xr = x + (size_t)b * 262144 + (row & 1023);
      float4v ex;
#pragma unroll
      for (int i = 0; i < 4; ++i) ex[i] = xr[(size_t)(lane * 4 + i) * 1024];
      double bs = 1e300; int bk = 0x7fffffff;
      for (int pass = 0; pass < 2; ++pass) {
        u64 bal = pass ? bal1 : bal0;
        unsigned src = pass ? lo : hi;
        while (bal) {
          int l = __ffsll((unsigned long long)bal) - 1;
          bal &= bal - 1;
          int kc = l * 128 + (int)(__shfl(src, l) & 127u);
          float4v wv4 = *(const float4v*)&w[(size_t)kc * DIM + lane * 4];
          double s = 0.0;
#pragma unroll
          for (int i = 0; i < 4; ++i) { double ev = (double)wv4[i]; s += ev * (ev - 2.0 * (double)ex[i]); }
#pragma unroll
          for (int d = 1; d < 64; d <<= 1) s += __shfl_xor(s, d);
          if (s < bs || (s == bs && kc < bk)) { bs = s; bk = kc; }
        }
      }
      kbest = bk;                                // all lanes agree (shuffle-reduced)
      d2c = bs;                                  // exact fp64
    }
    if (lane == 0) { out[CODE_OFF + row] = (float)kbest; dsum += d2c; }
    // inline gather: whole wave loads this row's e-vector (coalesced 256B x4)
    const float* wrow = w + (size_t)kbest * 256;
#pragma unroll
    for (int i = 0; i < 4; ++i) ect[(i * 64 + lane) * 65 + rl] = wrow[i * 64 + lane];
  }
  __syncthreads();

  // ---- phase 2: write xq (full-wave 256B txns); loss from scores, no x read
  const size_t base = (size_t)b * 262144 + n0 + lane;
  for (int j = 0; j < 16; ++j) {
    int c = wv * 16 + j;
    out[base + (size_t)c * 1024] = ect[c * 65 + lane];
  }
  if (lane == 0) dpart[wv] = dsum;
  __syncthreads();
  if (t == 0) {
    double s = 0.0;
#pragma unroll
    for (int i = 0; i < 16; ++i) s += dpart[i];
    atomicAdd(&dacc[0], s);
    __threadfence();
    oldc = atomicAdd(cnt, 1u);
  }
  __syncthreads();
  if (oldc == 255u && t < 64) {                  // last block: wave 0 finalizes
    float ps = 0.f;
#pragma unroll
    for (int i = 0; i < 8; ++i) ps += sxxp[t * 8 + i];
#pragma unroll
    for (int d = 32; d; d >>= 1) ps += __shfl_xor(ps, d);
    if (t == 0) {
      __threadfence();
      double sd2 = *(volatile double*)&dacc[0];
      out[LOSS_OFF] = (float)(1.25 * ((double)ps + sd2) / 4194304.0);
    }
  }
}

// ---------------------------------------------------------------- launch
extern "C" void kernel_launch(void* const* d_in, const int* in_sizes, int n_in,
                              void* d_out, int out_size, void* d_ws, size_t ws_size,
                              hipStream_t stream) {
  const float* x = (const float*)d_in[0];
  const float* w = (const float*)d_in[1];
  float* out = (float*)d_out;
  char* ws = (char*)d_ws;
  _Float16* xh   = (_Float16*)(ws);                 //  8,388,608 B (swizzled tiles)
  _Float16* eh   = (_Float16*)(ws + 8388608);       //  4,194,304 B (swizzled tiles)
  float*    en2c = (float*)(ws + 12582912);         //     32,768 B
  u64*      top2 = (u64*)(ws + 12615680);           //  8,388,608 B ([64 bx][16384 row] u64)
  float*    sxxp = (float*)(ws + 21004288);         //      2,048 B (512 partials)
  double*   dacc = (double*)(ws + 21006336);        //          8 B (sum d2)
  unsigned* cnt  = (unsigned*)(ws + 21006344);      //          4 B

  k_prep<<<768, 256, 0, stream>>>(x, xh, w, eh, en2c, sxxp, dacc, cnt);
  k_gemm<<<dim3(64, 128), 256, 0, stream>>>(xh, eh, en2c, top2);
  k_out<<<256, 1024, 0, stream>>>(top2, x, w, out, sxxp, dacc, cnt);
}